// Round 6
// baseline (371.411 us; speedup 1.0000x reference)
//
#include <hip/hip_runtime.h>
#include <hip/hip_fp16.h>

#define D 128
#define N_NODES 50000
#define EPSP1 1.1f

// ---- bucketed CSR-build parameters ----
#define NPB 128                 // nodes per bucket (dst >> 7)
#define NBUCK 391               // ceil(50000/128)
#define CAP 2560                // staging cap per bucket (mean 2046, std ~45)
#define P1E 4096                // edges per pass-1 unit (8 per thread, 512 thr)
#define TS 136                  // LDS tile row stride (bf16 elems)
#define PGRID 512               // persistent grid: 2 blocks/CU guaranteed by
                                // __launch_bounds__(512,4) (VGPR<=128) + 35KB LDS

typedef __attribute__((ext_vector_type(8))) short short8;   // 8 bf16 (4 VGPRs)
typedef __attribute__((ext_vector_type(4))) float f32x4;    // MFMA accumulator

__device__ __forceinline__ unsigned short f2bf(float f) {
    unsigned u = __float_as_uint(f);
    u += 0x7FFF + ((u >> 16) & 1);          // round-to-nearest-even
    return (unsigned short)(u >> 16);
}
__device__ __forceinline__ float bf2f(unsigned short h) {
    return __uint_as_float(((unsigned)h) << 16);
}

// ---------------------------------------------------------------------------
// Grid barrier, graph-capture-safe: monotonic counting barrier.  bar is
// zeroed by the hipMemsetAsync that precedes this kernel in the stream
// (and thus in the captured graph), so replays are safe.  No reset needed
// between consecutive barriers: each instance consumes exactly PGRID
// increments, and a block passes barrier k only when all PGRID blocks
// arrived.  __syncthreads drains vmcnt(0) -> all block writes are in the
// XCD L2; thread 0's __threadfence (agent scope) does the L2
// writeback/invalidate for cross-XCD visibility.
// ---------------------------------------------------------------------------
__device__ __forceinline__ void gsync(unsigned* bar) {
    __syncthreads();
    if (threadIdx.x == 0) {
        __threadfence();                               // release (wb L2)
        unsigned old = atomicAdd(bar, 1u);
        unsigned tgt = (old / PGRID + 1u) * PGRID;
        while (__hip_atomic_load(bar, __ATOMIC_RELAXED,
                                 __HIP_MEMORY_SCOPE_AGENT) < tgt)
            __builtin_amdgcn_s_sleep(2);
        __threadfence();                               // acquire (inv L1/L2)
    }
    __syncthreads();
}

// ---- LDS phase union (17.5 KB) ----
struct SmemP1 { int bcnt[NBUCK]; int goff[NBUCK]; };
struct SmemCsr {
    int hist[NPB]; int scn[NPB]; int loc[NPB];
    int wtot[2]; int base_s;
    unsigned csr[CAP];                      // 10 KB
};
struct SmemConv {
    unsigned short t1[32 * TS];             // 8.5 KB  z tile
    unsigned short t2[32 * TS];             // 8.5 KB  relu(GEMM1) tile
    int offs[33];
};
union SmemAll { SmemP1 p1; SmemCsr c; SmemConv v; };

// ---------------------------------------------------------------------------
// Phase-1 unit: [0,nb1) edge bucketing; [nb1,nb1+ncvt) x fp32->bf16;
// [nb1+ncvt, ...) weight pack.  512 threads.
// ---------------------------------------------------------------------------
__device__ __forceinline__ void p1_unit(
    int u, int nb1, int ncvt, SmemAll& sm,
    const int* __restrict__ src, const int* __restrict__ dst,
    const float* __restrict__ ew, int* __restrict__ gcnt,
    uint2* __restrict__ gstage, int ne,
    const float* __restrict__ x, unsigned short* __restrict__ hb, int n4,
    const float* __restrict__ W1a, const float* __restrict__ W1b,
    const float* __restrict__ W2a, const float* __restrict__ W2b,
    unsigned short* __restrict__ wp)
{
    int tid = threadIdx.x;
    if (u < nb1) {
        // ================= edge bucketing (8 edges/thread) =================
        for (int i = tid; i < NBUCK; i += 512) sm.p1.bcnt[i] = 0;
        __syncthreads();
        int e0 = u * P1E;
        int   rank[8];
        int   buck[8];
        uint2 pay[8];
#pragma unroll
        for (int j = 0; j < 8; ++j) {
            int e = e0 + j * 512 + tid;
            buck[j] = -1;
            if (e < ne) {
                int d_ = dst[e];
                int b  = d_ >> 7;
                int dl = d_ & 127;
                pay[j].x = (unsigned)(src[e] & 0xFFFF) | ((unsigned)dl << 16);
                pay[j].y = (unsigned)__half_as_ushort(__float2half_rn(ew[e]));
                rank[j]  = atomicAdd(&sm.p1.bcnt[b], 1);
                buck[j]  = b;
            }
        }
        __syncthreads();
        for (int i = tid; i < NBUCK; i += 512)
            if (sm.p1.bcnt[i] > 0) sm.p1.goff[i] = atomicAdd(&gcnt[i], sm.p1.bcnt[i]);
        __syncthreads();
#pragma unroll
        for (int j = 0; j < 8; ++j) {
            if (buck[j] >= 0) {
                int pos = sm.p1.goff[buck[j]] + rank[j];
                if (pos < CAP)
                    gstage[(size_t)buck[j] * CAP + pos] = pay[j];
            }
        }
        __syncthreads();            // protect LDS before next unit reuses it
    } else if (u < nb1 + ncvt) {
        // ================= x fp32 -> bf16 =================
        int base = (u - nb1) * 4096;       // float4 units
#pragma unroll
        for (int it = 0; it < 8; ++it) {
            int i = base + it * 512 + tid;
            if (i < n4) {
                float4 v = ((const float4*)x)[i];
                ushort4 o;
                o.x = f2bf(v.x); o.y = f2bf(v.y); o.z = f2bf(v.z); o.w = f2bf(v.w);
                ((ushort4*)hb)[i] = o;
            }
        }
    } else {
        // ================= weight pack =================
        int e2 = (u - nb1 - ncvt) * 512 + tid;    // 0..8191
        if (e2 < 8192) {
            int mat = e2 >> 11;                   // 0..3
            int e   = e2 & 2047;
            const float* W = (mat == 0) ? W1a : (mat == 1) ? W1b : (mat == 2) ? W2a : W2b;
            unsigned short* Wp = wp + (size_t)mat * 16384;
            int col = e & 127;
            int kq  = e >> 7;
            short8 v;
#pragma unroll
            for (int j = 0; j < 8; ++j)
                v[j] = (short)f2bf(W[(size_t)(kq * 8 + j) * 128 + col]);
            ((short8*)Wp)[e] = v;
        }
    }
}

// ---------------------------------------------------------------------------
// Phase-2 unit: CSR build for one bucket (shuffle-scan), 512 threads.
// ---------------------------------------------------------------------------
__device__ __forceinline__ void csr_unit(
    int b, SmemAll& sm,
    const uint2* __restrict__ gstage, const int* __restrict__ gcnt,
    unsigned* __restrict__ epay, int* __restrict__ off)
{
    int t = threadIdx.x;
    int cnt = min(gcnt[b], CAP);

    if (t < NPB) sm.c.hist[t] = 0;
    __syncthreads();

    uint2 ent[CAP / 512];                  // 5
#pragma unroll
    for (int it = 0; it < CAP / 512; ++it) {
        int i = it * 512 + t;
        if (i < cnt) {
            ent[it] = gstage[(size_t)b * CAP + i];
            atomicAdd(&sm.c.hist[(ent[it].x >> 16) & 255], 1);
        }
    }
    __syncthreads();

    int w = t >> 6, l = t & 63;
    if (w < 2) {
        // waves 0-1: inclusive shuffle-scan of hist[w*64 .. w*64+63]
        int v = sm.c.hist[w * 64 + l];
#pragma unroll
        for (int dd = 1; dd < 64; dd <<= 1) {
            int u = __shfl_up(v, dd, 64);
            if (l >= dd) v += u;
        }
        sm.c.scn[w * 64 + l] = v;
        if (l == 63) sm.c.wtot[w] = v;
    } else if (w == 2) {
        // wave 2: base = sum of preceding bucket counts
        int v = 0;
        for (int i = l; i < NBUCK; i += 64)
            if (i < b) v += min(gcnt[i], CAP);
#pragma unroll
        for (int dd = 32; dd > 0; dd >>= 1) v += __shfl_down(v, dd, 64);
        if (l == 0) sm.c.base_s = v;
    }
    __syncthreads();

    if (t < NPB) {
        int pre = (t >= 64) ? sm.c.wtot[0] : 0;
        int incl = sm.c.scn[t] + pre;
        int excl = incl - sm.c.hist[t];
        int node = (b << 7) + t;
        if (node <= N_NODES) off[node] = sm.c.base_s + excl;
        sm.c.loc[t] = excl;
    }
    __syncthreads();

#pragma unroll
    for (int it = 0; it < CAP / 512; ++it) {
        int i = it * 512 + t;
        if (i < cnt) {
            int dl = (ent[it].x >> 16) & 255;
            int p = atomicAdd(&sm.c.loc[dl], 1);
            sm.c.csr[p] = (ent[it].x & 0xFFFF) | (ent[it].y << 16);
        }
    }
    __syncthreads();

    int base_s = sm.c.base_s;
    for (int i = t; i < cnt; i += 512)
        epay[base_s + i] = sm.c.csr[i];
    __syncthreads();               // protect LDS before next unit reuses it
}

// ---------------------------------------------------------------------------
// Phase-3/4 unit: fused GIN conv tile (32 nodes, 8 waves, one node per
// 16-lane quarter; each wave owns one output column-group).
// ---------------------------------------------------------------------------
template<int RELU2, int OUT_F32>
__device__ __forceinline__ void conv_unit(
    int u, SmemAll& sm,
    const unsigned short* __restrict__ h, const int* __restrict__ off,
    const unsigned* __restrict__ epay,
    const unsigned short* __restrict__ WpA,
    const unsigned short* __restrict__ WpB,
    void* __restrict__ outv, int n)
{
    int tid  = threadIdx.x;
    int wave = tid >> 6;
    int lane = tid & 63;
    int qtr  = lane >> 4;       // 0..3 (== MFMA quad)
    int sub  = lane & 15;       // (== MFMA lc)
    int nb   = u * 32;

    if (tid < 33) sm.v.offs[tid] = off[min(nb + tid, n)];
    __syncthreads();

    // ================= gather: one node per quarter =================
    int row  = wave * 4 + qtr;  // 0..31
    int node = nb + row;
    int beg = sm.v.offs[row];
    int end = sm.v.offs[row + 1];

    float acc[8];
#pragma unroll
    for (int c = 0; c < 8; ++c) acc[c] = 0.f;

    int i = beg;
    for (; i + 4 <= end; i += 4) {          // 4 rows in flight per quarter
        unsigned p0 = epay[i];
        unsigned p1 = epay[i + 1];
        unsigned p2 = epay[i + 2];
        unsigned p3 = epay[i + 3];
        short8 v0 = ((const short8*)(h + (size_t)(p0 & 0xFFFF) * D))[sub];
        short8 v1 = ((const short8*)(h + (size_t)(p1 & 0xFFFF) * D))[sub];
        short8 v2 = ((const short8*)(h + (size_t)(p2 & 0xFFFF) * D))[sub];
        short8 v3 = ((const short8*)(h + (size_t)(p3 & 0xFFFF) * D))[sub];
        float w0 = __half2float(__ushort_as_half((unsigned short)(p0 >> 16)));
        float w1 = __half2float(__ushort_as_half((unsigned short)(p1 >> 16)));
        float w2 = __half2float(__ushort_as_half((unsigned short)(p2 >> 16)));
        float w3 = __half2float(__ushort_as_half((unsigned short)(p3 >> 16)));
#pragma unroll
        for (int c = 0; c < 8; ++c)
            acc[c] += w0 * bf2f((unsigned short)v0[c]) + w1 * bf2f((unsigned short)v1[c])
                    + w2 * bf2f((unsigned short)v2[c]) + w3 * bf2f((unsigned short)v3[c]);
    }
    for (; i < end; ++i) {                  // <=3 tail edges
        unsigned p0 = epay[i];
        short8 v0 = ((const short8*)(h + (size_t)(p0 & 0xFFFF) * D))[sub];
        float w0 = __half2float(__ushort_as_half((unsigned short)(p0 >> 16)));
#pragma unroll
        for (int c = 0; c < 8; ++c)
            acc[c] += w0 * bf2f((unsigned short)v0[c]);
    }

    // GIN update + store z row (each quarter owns a distinct row)
    {
        const short8 zero8 = {0, 0, 0, 0, 0, 0, 0, 0};
        short8 o;
        if (node < n) {
            short8 xv = ((const short8*)(h + (size_t)node * D))[sub];
#pragma unroll
            for (int c = 0; c < 8; ++c)
                o[c] = (short)f2bf(acc[c] + EPSP1 * bf2f((unsigned short)xv[c]));
        } else {
            o = zero8;
        }
        *(short8*)&sm.v.t1[row * TS + sub * 8] = o;
    }
    __syncthreads();

    // ================= GEMM1: z @ WpA, relu -> t2 =================
    int cf = wave;              // this wave's column-group
    f32x4 acc2[2];
    acc2[0] = (f32x4){0.f, 0.f, 0.f, 0.f};
    acc2[1] = (f32x4){0.f, 0.f, 0.f, 0.f};

#pragma unroll
    for (int kk = 0; kk < 4; ++kk) {
        short8 a0 = *(const short8*)&sm.v.t1[(sub)      * TS + kk * 32 + qtr * 8];
        short8 a1 = *(const short8*)&sm.v.t1[(16 + sub) * TS + kk * 32 + qtr * 8];
        short8 b  = *(const short8*)(WpA + ((size_t)(kk * 4 + qtr) * 128 + cf * 16 + sub) * 8);
        acc2[0] = __builtin_amdgcn_mfma_f32_16x16x32_bf16(a0, b, acc2[0], 0, 0, 0);
        acc2[1] = __builtin_amdgcn_mfma_f32_16x16x32_bf16(a1, b, acc2[1], 0, 0, 0);
    }

#pragma unroll
    for (int s = 0; s < 2; ++s)
#pragma unroll
        for (int reg = 0; reg < 4; ++reg) {
            int r = s * 16 + qtr * 4 + reg;
            sm.v.t2[r * TS + cf * 16 + sub] = f2bf(fmaxf(acc2[s][reg], 0.f));
        }
    __syncthreads();

    // ================= GEMM2: relu(.) @ WpB =================
    acc2[0] = (f32x4){0.f, 0.f, 0.f, 0.f};
    acc2[1] = (f32x4){0.f, 0.f, 0.f, 0.f};

#pragma unroll
    for (int kk = 0; kk < 4; ++kk) {
        short8 a0 = *(const short8*)&sm.v.t2[(sub)      * TS + kk * 32 + qtr * 8];
        short8 a1 = *(const short8*)&sm.v.t2[(16 + sub) * TS + kk * 32 + qtr * 8];
        short8 b  = *(const short8*)(WpB + ((size_t)(kk * 4 + qtr) * 128 + cf * 16 + sub) * 8);
        acc2[0] = __builtin_amdgcn_mfma_f32_16x16x32_bf16(a0, b, acc2[0], 0, 0, 0);
        acc2[1] = __builtin_amdgcn_mfma_f32_16x16x32_bf16(a1, b, acc2[1], 0, 0, 0);
    }

#pragma unroll
    for (int s = 0; s < 2; ++s)
#pragma unroll
        for (int reg = 0; reg < 4; ++reg) {
            int r = nb + s * 16 + qtr * 4 + reg;
            if (r < n) {
                float v = acc2[s][reg];
                if (RELU2) v = fmaxf(v, 0.f);
                int col = cf * 16 + sub;
                if (OUT_F32)
                    ((float*)outv)[(size_t)r * D + col] = v;
                else
                    ((unsigned short*)outv)[(size_t)r * D + col] = f2bf(v);
            }
        }
    __syncthreads();               // protect LDS before next tile reuses it
}

// ---------------------------------------------------------------------------
// Persistent mega-kernel (plain launch + manual grid barrier): all former
// dispatches, phase-separated by gsync().
// ---------------------------------------------------------------------------
__global__ __launch_bounds__(512, 4) void gin_mega(
    const int* __restrict__ src, const int* __restrict__ dst,
    const float* __restrict__ ew, int* __restrict__ gcnt,
    uint2* __restrict__ gstage, int ne, int nb1,
    const float* __restrict__ x, unsigned short* __restrict__ hb,
    int n4, int ncvt,
    const float* __restrict__ W1a, const float* __restrict__ W1b,
    const float* __restrict__ W2a, const float* __restrict__ W2b,
    unsigned short* __restrict__ wp,
    unsigned* __restrict__ epay, int* __restrict__ off,
    unsigned short* __restrict__ zb, float* __restrict__ out,
    unsigned* __restrict__ bar)
{
    __shared__ SmemAll sm;

    int bid = blockIdx.x;
    int cgridn = (N_NODES + 31) / 32;       // 1563 conv tiles

    // ---- phase 1: bucket | x->bf16 | weight pack  (gcnt zeroed by memset)
    int p1units = nb1 + ncvt + 16;
    for (int u = bid; u < p1units; u += PGRID)
        p1_unit(u, nb1, ncvt, sm, src, dst, ew, gcnt, gstage, ne,
                x, hb, n4, W1a, W1b, W2a, W2b, wp);
    gsync(bar);

    // ---- phase 2: CSR build
    for (int u = bid; u < NBUCK; u += PGRID)
        csr_unit(u, sm, gstage, gcnt, epay, off);
    gsync(bar);

    // ---- phase 3: conv 1  (hb -> zb, inter-conv relu fused)
    const unsigned short* wp0 = wp;
    const unsigned short* wp1 = wp + 16384;
    for (int u = bid; u < cgridn; u += PGRID)
        conv_unit<1, 0>(u, sm, hb, off, epay, wp0, wp1, (void*)zb, N_NODES);
    gsync(bar);

    // ---- phase 4: conv 2  (zb -> out, fp32)
    const unsigned short* wp2 = wp + 2 * 16384;
    const unsigned short* wp3 = wp + 3 * 16384;
    for (int u = bid; u < cgridn; u += PGRID)
        conv_unit<0, 1>(u, sm, zb, off, epay, wp2, wp3, (void*)out, N_NODES);
}

extern "C" void kernel_launch(void* const* d_in, const int* in_sizes, int n_in,
                              void* d_out, int out_size, void* d_ws, size_t ws_size,
                              hipStream_t stream) {
    const float* x   = (const float*)d_in[0];
    const int*   ei  = (const int*)d_in[1];
    const float* ew  = (const float*)d_in[2];
    const float* W1a = (const float*)d_in[3];
    const float* W1b = (const float*)d_in[4];
    const float* W2a = (const float*)d_in[5];
    const float* W2b = (const float*)d_in[6];
    float* out = (float*)d_out;

    int n_edges = in_sizes[2];                 // 800000
    const int* src = ei;
    const int* dst = ei + n_edges;

    size_t node_elems = (size_t)N_NODES * D;   // 6.4M
    unsigned short* hb = (unsigned short*)d_ws;        // 12.8 MB  bf16 node features
    unsigned short* zb = hb + node_elems;              // 12.8 MB  conv1 output (bf16)
    unsigned short* wp = zb + node_elems;              // 4 x 32 KB packed weights
    unsigned* epay = (unsigned*)(wp + 4 * 16384);      // E x 4B final CSR payload
    uint2*  gstage = (uint2*)(epay + n_edges);         // NBUCK x CAP x 8B staging
    int*    gcnt   = (int*)(gstage + (size_t)NBUCK * CAP);  // NBUCK
    unsigned* bar  = (unsigned*)(gcnt + NBUCK);        // 1 (grid barrier)
    int*    off    = (int*)(bar + 1);                  // N+1

    int nb1   = (n_edges + P1E - 1) / P1E;              // 196
    int n4    = (int)(node_elems / 4);                  // 1.6M float4
    int ncvt  = (n4 + 4095) / 4096;                     // 391

    // zero gcnt + barrier counter in one memset (precedes kernel in graph)
    hipMemsetAsync(gcnt, 0, (NBUCK + 1) * sizeof(int), stream);

    gin_mega<<<PGRID, 512, 0, stream>>>(
        src, dst, ew, gcnt, gstage, n_edges, nb1,
        x, hb, n4, ncvt, W1a, W1b, W2a, W2b, wp,
        epay, off, zb, out, bar);
}

// Round 7
// 192.127 us; speedup vs baseline: 1.9332x; 1.9332x over previous
//
#include <hip/hip_runtime.h>
#include <hip/hip_fp16.h>

#define D 128
#define N_NODES 50000
#define EPSP1 1.1f

// ---- bucketed CSR-build parameters ----
#define NPB 128                 // nodes per bucket (dst >> 7)
#define NBUCK 391               // ceil(50000/128)
#define CAP 2560                // staging cap per bucket (mean 2046, std ~45)
#define P1E 4096                // edges per pass-1 block (8 per thread, 512 thr)
#define TS 136                  // LDS tile row stride (bf16 elems)

typedef __attribute__((ext_vector_type(8))) short short8;   // 8 bf16 (4 VGPRs)
typedef __attribute__((ext_vector_type(4))) float f32x4;    // MFMA accumulator

__device__ __forceinline__ unsigned short f2bf(float f) {
    unsigned u = __float_as_uint(f);
    u += 0x7FFF + ((u >> 16) & 1);          // round-to-nearest-even
    return (unsigned short)(u >> 16);
}
__device__ __forceinline__ float bf2f(unsigned short h) {
    return __uint_as_float(((unsigned)h) << 16);
}

// ---------------------------------------------------------------------------
// Pass 1 (merged, 512 thr): blocks [0,nb1) edge bucketing; [nb1,nb1+ncvt)
// x fp32->bf16; rest weight pack.
// ---------------------------------------------------------------------------
__global__ __launch_bounds__(512, 4) void pass1_all(
    const int* __restrict__ src, const int* __restrict__ dst,
    const float* __restrict__ ew, int* __restrict__ gcnt,
    uint2* __restrict__ gstage, int ne, int nb1,
    const float* __restrict__ x, unsigned short* __restrict__ hb,
    int n4, int ncvt,
    const float* __restrict__ W1a, const float* __restrict__ W1b,
    const float* __restrict__ W2a, const float* __restrict__ W2b,
    unsigned short* __restrict__ wp)
{
    __shared__ int bcnt[NBUCK];
    __shared__ int goff[NBUCK];
    int tid = threadIdx.x;
    int bid = blockIdx.x;

    if (bid < nb1) {
        // ================= edge bucketing (8 edges/thread) =================
        for (int i = tid; i < NBUCK; i += 512) bcnt[i] = 0;
        __syncthreads();
        int e0 = bid * P1E;
        int   rank[8];
        int   buck[8];
        uint2 pay[8];
#pragma unroll
        for (int j = 0; j < 8; ++j) {
            int e = e0 + j * 512 + tid;
            buck[j] = -1;
            if (e < ne) {
                int d_ = dst[e];
                int b  = d_ >> 7;
                int dl = d_ & 127;
                pay[j].x = (unsigned)(src[e] & 0xFFFF) | ((unsigned)dl << 16);
                pay[j].y = (unsigned)__half_as_ushort(__float2half_rn(ew[e]));
                rank[j]  = atomicAdd(&bcnt[b], 1);
                buck[j]  = b;
            }
        }
        __syncthreads();
        for (int i = tid; i < NBUCK; i += 512)
            if (bcnt[i] > 0) goff[i] = atomicAdd(&gcnt[i], bcnt[i]);
        __syncthreads();
#pragma unroll
        for (int j = 0; j < 8; ++j) {
            if (buck[j] >= 0) {
                int pos = goff[buck[j]] + rank[j];
                if (pos < CAP)
                    gstage[(size_t)buck[j] * CAP + pos] = pay[j];
            }
        }
    } else if (bid < nb1 + ncvt) {
        // ================= x fp32 -> bf16 =================
        int base = (bid - nb1) * 4096;     // float4 units
#pragma unroll
        for (int it = 0; it < 8; ++it) {
            int i = base + it * 512 + tid;
            if (i < n4) {
                float4 v = ((const float4*)x)[i];
                ushort4 o;
                o.x = f2bf(v.x); o.y = f2bf(v.y); o.z = f2bf(v.z); o.w = f2bf(v.w);
                ((ushort4*)hb)[i] = o;
            }
        }
    } else {
        // ================= weight pack =================
        int e2 = (bid - nb1 - ncvt) * 512 + tid;  // 0..8191
        if (e2 < 8192) {
            int mat = e2 >> 11;                   // 0..3
            int e   = e2 & 2047;
            const float* W = (mat == 0) ? W1a : (mat == 1) ? W1b : (mat == 2) ? W2a : W2b;
            unsigned short* Wp = wp + (size_t)mat * 16384;
            int col = e & 127;
            int kq  = e >> 7;
            short8 v;
#pragma unroll
            for (int j = 0; j < 8; ++j)
                v[j] = (short)f2bf(W[(size_t)(kq * 8 + j) * 128 + col]);
            ((short8*)Wp)[e] = v;
        }
    }
}

// ---------------------------------------------------------------------------
// CSR build, direct-scatter version: rank captured at the counting atomic,
// final position = base + excl[bin] + rank, scattered straight to global
// epay (L2-absorbed, 8 KB window per bucket).  No csr[] LDS buffer, no loc
// atomic pass, no sequential copy -> bank-conflict hotspot removed
// (mega-kernel PMC: 1.05e7 conflict cycles, mostly here).
// ---------------------------------------------------------------------------
__global__ __launch_bounds__(512) void csr_build(
    const uint2* __restrict__ gstage, const int* __restrict__ gcnt,
    unsigned* __restrict__ epay, int* __restrict__ off)
{
    __shared__ int hist[NPB];
    __shared__ int scn[NPB];
    __shared__ int exc[NPB];
    __shared__ int wtot[2];
    __shared__ int base_s;

    int b = blockIdx.x;
    int t = threadIdx.x;
    int cnt = min(gcnt[b], CAP);

    if (t < NPB) hist[t] = 0;
    __syncthreads();

    uint2 ent[CAP / 512];                  // 5
    int   rnk[CAP / 512];
#pragma unroll
    for (int it = 0; it < CAP / 512; ++it) {
        int i = it * 512 + t;
        if (i < cnt) {
            ent[it] = gstage[(size_t)b * CAP + i];
            rnk[it] = atomicAdd(&hist[(ent[it].x >> 16) & 255], 1);
        }
    }
    __syncthreads();

    int w = t >> 6, l = t & 63;
    if (w < 2) {
        // waves 0-1: inclusive shuffle-scan of hist[w*64 .. w*64+63]
        int v = hist[w * 64 + l];
#pragma unroll
        for (int dd = 1; dd < 64; dd <<= 1) {
            int u = __shfl_up(v, dd, 64);
            if (l >= dd) v += u;
        }
        scn[w * 64 + l] = v;
        if (l == 63) wtot[w] = v;
    } else if (w == 2) {
        // wave 2: base = sum of preceding bucket counts
        int v = 0;
        for (int i = l; i < NBUCK; i += 64)
            if (i < b) v += min(gcnt[i], CAP);
#pragma unroll
        for (int dd = 32; dd > 0; dd >>= 1) v += __shfl_down(v, dd, 64);
        if (l == 0) base_s = v;
    }
    __syncthreads();

    if (t < NPB) {
        int pre = (t >= 64) ? wtot[0] : 0;
        int incl = scn[t] + pre;
        int excl = incl - hist[t];
        int node = (b << 7) + t;
        if (node <= N_NODES) off[node] = base_s + excl;
        exc[t] = excl;
    }
    __syncthreads();

    int base_s_r = base_s;
#pragma unroll
    for (int it = 0; it < CAP / 512; ++it) {
        int i = it * 512 + t;
        if (i < cnt) {
            int dl = (ent[it].x >> 16) & 255;
            epay[base_s_r + exc[dl] + rnk[it]] =
                (ent[it].x & 0xFFFF) | (ent[it].y << 16);
        }
    }
}

// ---------------------------------------------------------------------------
// Fused GIN conv:
//   block = 32 nodes, 512 threads = 8 waves; one node per 16-lane quarter.
//   Gather unrolled to 8 rows in flight per quarter (mega-kernel PMC showed
//   the workload is concurrency-limited: throughput ~ outstanding loads).
//   __launch_bounds__(512,8) caps VGPR at 64 -> 4 blocks/CU (32 waves) held.
//   MLP: shared 32-row tile; each wave owns one output column-group.
// ---------------------------------------------------------------------------
template<int RELU2, int OUT_F32>
__global__ __launch_bounds__(512, 8) void conv_fused(
    const unsigned short* __restrict__ h, const int* __restrict__ off,
    const unsigned* __restrict__ epay,
    const unsigned short* __restrict__ WpA,
    const unsigned short* __restrict__ WpB,
    void* __restrict__ outv, int n)
{
    __shared__ unsigned short t1[32 * TS];   // 8.5 KB  z tile
    __shared__ unsigned short t2[32 * TS];   // 8.5 KB  relu(GEMM1) tile
    __shared__ int offs[33];

    int tid  = threadIdx.x;
    int wave = tid >> 6;
    int lane = tid & 63;
    int qtr  = lane >> 4;       // 0..3 (== MFMA quad)
    int sub  = lane & 15;       // (== MFMA lc)
    int nb   = blockIdx.x * 32;

    if (tid < 33) offs[tid] = off[min(nb + tid, n)];
    __syncthreads();

    // ================= gather: one node per quarter, 8-deep =================
    int row  = wave * 4 + qtr;  // 0..31
    int node = nb + row;
    int beg = offs[row];
    int end = offs[row + 1];

    float acc[8];
#pragma unroll
    for (int c = 0; c < 8; ++c) acc[c] = 0.f;

    int i = beg;
    for (; i + 8 <= end; i += 8) {          // 8 rows in flight per quarter
        unsigned p0 = epay[i];
        unsigned p1 = epay[i + 1];
        unsigned p2 = epay[i + 2];
        unsigned p3 = epay[i + 3];
        unsigned p4 = epay[i + 4];
        unsigned p5 = epay[i + 5];
        unsigned p6 = epay[i + 6];
        unsigned p7 = epay[i + 7];
        short8 v0 = ((const short8*)(h + (size_t)(p0 & 0xFFFF) * D))[sub];
        short8 v1 = ((const short8*)(h + (size_t)(p1 & 0xFFFF) * D))[sub];
        short8 v2 = ((const short8*)(h + (size_t)(p2 & 0xFFFF) * D))[sub];
        short8 v3 = ((const short8*)(h + (size_t)(p3 & 0xFFFF) * D))[sub];
        short8 v4 = ((const short8*)(h + (size_t)(p4 & 0xFFFF) * D))[sub];
        short8 v5 = ((const short8*)(h + (size_t)(p5 & 0xFFFF) * D))[sub];
        short8 v6 = ((const short8*)(h + (size_t)(p6 & 0xFFFF) * D))[sub];
        short8 v7 = ((const short8*)(h + (size_t)(p7 & 0xFFFF) * D))[sub];
        float w0 = __half2float(__ushort_as_half((unsigned short)(p0 >> 16)));
        float w1 = __half2float(__ushort_as_half((unsigned short)(p1 >> 16)));
        float w2 = __half2float(__ushort_as_half((unsigned short)(p2 >> 16)));
        float w3 = __half2float(__ushort_as_half((unsigned short)(p3 >> 16)));
        float w4 = __half2float(__ushort_as_half((unsigned short)(p4 >> 16)));
        float w5 = __half2float(__ushort_as_half((unsigned short)(p5 >> 16)));
        float w6 = __half2float(__ushort_as_half((unsigned short)(p6 >> 16)));
        float w7 = __half2float(__ushort_as_half((unsigned short)(p7 >> 16)));
#pragma unroll
        for (int c = 0; c < 8; ++c)
            acc[c] += w0 * bf2f((unsigned short)v0[c]) + w1 * bf2f((unsigned short)v1[c])
                    + w2 * bf2f((unsigned short)v2[c]) + w3 * bf2f((unsigned short)v3[c])
                    + w4 * bf2f((unsigned short)v4[c]) + w5 * bf2f((unsigned short)v5[c])
                    + w6 * bf2f((unsigned short)v6[c]) + w7 * bf2f((unsigned short)v7[c]);
    }
    for (; i + 4 <= end; i += 4) {          // 4 rows in flight
        unsigned p0 = epay[i];
        unsigned p1 = epay[i + 1];
        unsigned p2 = epay[i + 2];
        unsigned p3 = epay[i + 3];
        short8 v0 = ((const short8*)(h + (size_t)(p0 & 0xFFFF) * D))[sub];
        short8 v1 = ((const short8*)(h + (size_t)(p1 & 0xFFFF) * D))[sub];
        short8 v2 = ((const short8*)(h + (size_t)(p2 & 0xFFFF) * D))[sub];
        short8 v3 = ((const short8*)(h + (size_t)(p3 & 0xFFFF) * D))[sub];
        float w0 = __half2float(__ushort_as_half((unsigned short)(p0 >> 16)));
        float w1 = __half2float(__ushort_as_half((unsigned short)(p1 >> 16)));
        float w2 = __half2float(__ushort_as_half((unsigned short)(p2 >> 16)));
        float w3 = __half2float(__ushort_as_half((unsigned short)(p3 >> 16)));
#pragma unroll
        for (int c = 0; c < 8; ++c)
            acc[c] += w0 * bf2f((unsigned short)v0[c]) + w1 * bf2f((unsigned short)v1[c])
                    + w2 * bf2f((unsigned short)v2[c]) + w3 * bf2f((unsigned short)v3[c]);
    }
    for (; i < end; ++i) {                  // <=3 tail edges
        unsigned p0 = epay[i];
        short8 v0 = ((const short8*)(h + (size_t)(p0 & 0xFFFF) * D))[sub];
        float w0 = __half2float(__ushort_as_half((unsigned short)(p0 >> 16)));
#pragma unroll
        for (int c = 0; c < 8; ++c)
            acc[c] += w0 * bf2f((unsigned short)v0[c]);
    }

    // GIN update + store z row (each quarter owns a distinct row)
    {
        const short8 zero8 = {0, 0, 0, 0, 0, 0, 0, 0};
        short8 o;
        if (node < n) {
            short8 xv = ((const short8*)(h + (size_t)node * D))[sub];
#pragma unroll
            for (int c = 0; c < 8; ++c)
                o[c] = (short)f2bf(acc[c] + EPSP1 * bf2f((unsigned short)xv[c]));
        } else {
            o = zero8;
        }
        *(short8*)&t1[row * TS + sub * 8] = o;
    }
    __syncthreads();

    // ================= GEMM1: z @ WpA, relu -> t2 =================
    int cf = wave;              // this wave's column-group
    f32x4 acc2[2];
    acc2[0] = (f32x4){0.f, 0.f, 0.f, 0.f};
    acc2[1] = (f32x4){0.f, 0.f, 0.f, 0.f};

#pragma unroll
    for (int kk = 0; kk < 4; ++kk) {
        short8 a0 = *(const short8*)&t1[(sub)      * TS + kk * 32 + qtr * 8];
        short8 a1 = *(const short8*)&t1[(16 + sub) * TS + kk * 32 + qtr * 8];
        short8 b  = *(const short8*)(WpA + ((size_t)(kk * 4 + qtr) * 128 + cf * 16 + sub) * 8);
        acc2[0] = __builtin_amdgcn_mfma_f32_16x16x32_bf16(a0, b, acc2[0], 0, 0, 0);
        acc2[1] = __builtin_amdgcn_mfma_f32_16x16x32_bf16(a1, b, acc2[1], 0, 0, 0);
    }

#pragma unroll
    for (int s = 0; s < 2; ++s)
#pragma unroll
        for (int reg = 0; reg < 4; ++reg) {
            int r = s * 16 + qtr * 4 + reg;
            t2[r * TS + cf * 16 + sub] = f2bf(fmaxf(acc2[s][reg], 0.f));
        }
    __syncthreads();

    // ================= GEMM2: relu(.) @ WpB =================
    acc2[0] = (f32x4){0.f, 0.f, 0.f, 0.f};
    acc2[1] = (f32x4){0.f, 0.f, 0.f, 0.f};

#pragma unroll
    for (int kk = 0; kk < 4; ++kk) {
        short8 a0 = *(const short8*)&t2[(sub)      * TS + kk * 32 + qtr * 8];
        short8 a1 = *(const short8*)&t2[(16 + sub) * TS + kk * 32 + qtr * 8];
        short8 b  = *(const short8*)(WpB + ((size_t)(kk * 4 + qtr) * 128 + cf * 16 + sub) * 8);
        acc2[0] = __builtin_amdgcn_mfma_f32_16x16x32_bf16(a0, b, acc2[0], 0, 0, 0);
        acc2[1] = __builtin_amdgcn_mfma_f32_16x16x32_bf16(a1, b, acc2[1], 0, 0, 0);
    }

#pragma unroll
    for (int s = 0; s < 2; ++s)
#pragma unroll
        for (int reg = 0; reg < 4; ++reg) {
            int r = nb + s * 16 + qtr * 4 + reg;
            if (r < n) {
                float v = acc2[s][reg];
                if (RELU2) v = fmaxf(v, 0.f);
                int col = cf * 16 + sub;
                if (OUT_F32)
                    ((float*)outv)[(size_t)r * D + col] = v;
                else
                    ((unsigned short*)outv)[(size_t)r * D + col] = f2bf(v);
            }
        }
}

extern "C" void kernel_launch(void* const* d_in, const int* in_sizes, int n_in,
                              void* d_out, int out_size, void* d_ws, size_t ws_size,
                              hipStream_t stream) {
    const float* x   = (const float*)d_in[0];
    const int*   ei  = (const int*)d_in[1];
    const float* ew  = (const float*)d_in[2];
    const float* W1a = (const float*)d_in[3];
    const float* W1b = (const float*)d_in[4];
    const float* W2a = (const float*)d_in[5];
    const float* W2b = (const float*)d_in[6];
    float* out = (float*)d_out;

    int n_edges = in_sizes[2];                 // 800000
    const int* src = ei;
    const int* dst = ei + n_edges;

    size_t node_elems = (size_t)N_NODES * D;   // 6.4M
    unsigned short* hb = (unsigned short*)d_ws;        // 12.8 MB  bf16 node features
    unsigned short* zb = hb + node_elems;              // 12.8 MB  conv1 output (bf16)
    unsigned short* wp = zb + node_elems;              // 4 x 32 KB packed weights
    unsigned* epay = (unsigned*)(wp + 4 * 16384);      // E x 4B final CSR payload
    uint2*  gstage = (uint2*)(epay + n_edges);         // NBUCK x CAP x 8B staging
    int*    gcnt   = (int*)(gstage + (size_t)NBUCK * CAP);  // NBUCK
    int*    off    = gcnt + NBUCK;                     // N+1

    int nb1   = (n_edges + P1E - 1) / P1E;              // 196
    int n4    = (int)(node_elems / 4);                  // 1.6M float4
    int ncvt  = (n4 + 4095) / 4096;                     // 391
    int npack = 16;                                     // 8192 short8 / 512
    int cgrid = (N_NODES + 31) / 32;                    // 1563

    hipMemsetAsync(gcnt, 0, NBUCK * sizeof(int), stream);

    // ---- pass 1 (merged): bucket | x->bf16 | weight pack
    pass1_all<<<nb1 + ncvt + npack, 512, 0, stream>>>(
        src, dst, ew, gcnt, gstage, n_edges, nb1,
        x, hb, n4, ncvt, W1a, W1b, W2a, W2b, wp);

    // ---- CSR build (direct global scatter)
    csr_build<<<NBUCK, 512, 0, stream>>>(gstage, gcnt, epay, off);

    unsigned short* wp0 = wp;
    unsigned short* wp1 = wp + 16384;
    unsigned short* wp2 = wp + 2 * 16384;
    unsigned short* wp3 = wp + 3 * 16384;

    // ---- conv 1 (fused gather + GIN update + MLP, inter-conv relu fused)
    conv_fused<1, 0><<<cgrid, 512, 0, stream>>>(hb, off, epay, wp0, wp1, zb, N_NODES);

    // ---- conv 2 (fp32 out, no final relu)
    conv_fused<0, 1><<<cgrid, 512, 0, stream>>>(zb, off, epay, wp2, wp3, out, N_NODES);
}

// Round 8
// 179.272 us; speedup vs baseline: 2.0718x; 1.0717x over previous
//
#include <hip/hip_runtime.h>
#include <hip/hip_fp16.h>

#define D 128
#define N_NODES 50000
#define EPSP1 1.1f

// ---- per-tile bucketing parameters (bucket == 32-node conv tile) ----
#define NPB 32                  // nodes per bucket (dst >> 5)
#define NBUCK 1563              // ceil(50000/32)
#define CAP 768                 // staging cap per bucket (mean 512, +11 sigma)
#define P1E 4096                // edges per pass-1 block (8 per thread, 512 thr)
#define TS 136                  // LDS tile row stride (bf16 elems)

typedef __attribute__((ext_vector_type(8))) short short8;   // 8 bf16 (4 VGPRs)
typedef __attribute__((ext_vector_type(4))) float f32x4;    // MFMA accumulator

__device__ __forceinline__ unsigned short f2bf(float f) {
    unsigned u = __float_as_uint(f);
    u += 0x7FFF + ((u >> 16) & 1);          // round-to-nearest-even
    return (unsigned short)(u >> 16);
}
__device__ __forceinline__ float bf2f(unsigned short h) {
    return __uint_as_float(((unsigned)h) << 16);
}

// ---------------------------------------------------------------------------
// Pass 1 (merged, 512 thr): blocks [0,nb1) edge bucketing into per-TILE
// buckets; [nb1,nb1+ncvt) x fp32->bf16; rest weight pack.
// ---------------------------------------------------------------------------
__global__ __launch_bounds__(512, 4) void pass1_all(
    const int* __restrict__ src, const int* __restrict__ dst,
    const float* __restrict__ ew, int* __restrict__ gcnt,
    uint2* __restrict__ gstage, int ne, int nb1,
    const float* __restrict__ x, unsigned short* __restrict__ hb,
    int n4, int ncvt,
    const float* __restrict__ W1a, const float* __restrict__ W1b,
    const float* __restrict__ W2a, const float* __restrict__ W2b,
    unsigned short* __restrict__ wp)
{
    __shared__ int bcnt[NBUCK];     // 6.3 KB
    __shared__ int goff[NBUCK];     // 6.3 KB
    int tid = threadIdx.x;
    int bid = blockIdx.x;

    if (bid < nb1) {
        // ================= edge bucketing (8 edges/thread) =================
        for (int i = tid; i < NBUCK; i += 512) bcnt[i] = 0;
        __syncthreads();
        int e0 = bid * P1E;
        int   rank[8];
        int   buck[8];
        uint2 pay[8];
#pragma unroll
        for (int j = 0; j < 8; ++j) {
            int e = e0 + j * 512 + tid;
            buck[j] = -1;
            if (e < ne) {
                int d_ = dst[e];
                int b  = d_ >> 5;
                int dl = d_ & 31;
                pay[j].x = (unsigned)(src[e] & 0xFFFF) | ((unsigned)dl << 16);
                pay[j].y = (unsigned)__half_as_ushort(__float2half_rn(ew[e]));
                rank[j]  = atomicAdd(&bcnt[b], 1);
                buck[j]  = b;
            }
        }
        __syncthreads();
        for (int i = tid; i < NBUCK; i += 512)
            if (bcnt[i] > 0) goff[i] = atomicAdd(&gcnt[i], bcnt[i]);
        __syncthreads();
#pragma unroll
        for (int j = 0; j < 8; ++j) {
            if (buck[j] >= 0) {
                int pos = goff[buck[j]] + rank[j];
                if (pos < CAP)
                    gstage[(size_t)buck[j] * CAP + pos] = pay[j];
            }
        }
    } else if (bid < nb1 + ncvt) {
        // ================= x fp32 -> bf16 =================
        int base = (bid - nb1) * 4096;     // float4 units
#pragma unroll
        for (int it = 0; it < 8; ++it) {
            int i = base + it * 512 + tid;
            if (i < n4) {
                float4 v = ((const float4*)x)[i];
                ushort4 o;
                o.x = f2bf(v.x); o.y = f2bf(v.y); o.z = f2bf(v.z); o.w = f2bf(v.w);
                ((ushort4*)hb)[i] = o;
            }
        }
    } else {
        // ================= weight pack =================
        int e2 = (bid - nb1 - ncvt) * 512 + tid;  // 0..8191
        if (e2 < 8192) {
            int mat = e2 >> 11;                   // 0..3
            int e   = e2 & 2047;
            const float* W = (mat == 0) ? W1a : (mat == 1) ? W1b : (mat == 2) ? W2a : W2b;
            unsigned short* Wp = wp + (size_t)mat * 16384;
            int col = e & 127;
            int kq  = e >> 7;
            short8 v;
#pragma unroll
            for (int j = 0; j < 8; ++j)
                v[j] = (short)f2bf(W[(size_t)(kq * 8 + j) * 128 + col]);
            ((short8*)Wp)[e] = v;
        }
    }
}

// ---------------------------------------------------------------------------
// Fused GIN conv with in-block mini-sort (csr_build + epay + off eliminated):
//   block = 32 nodes = one bucket, 512 threads = 8 waves.
//   1. stage this bucket's ~512 raw entries from gstage,
//      rank-at-count into hist[32], 32-lane shuffle scan, scatter into a
//      sorted LDS list (payload = src | w<<16).
//   2. gather: one node per 16-lane quarter, 8-deep, payloads from LDS
//      (quarter-uniform broadcast reads).
//   3. 2-layer MFMA MLP on the shared 32-row tile (each wave owns one
//      output column-group).
// ---------------------------------------------------------------------------
template<int RELU2, int OUT_F32>
__global__ __launch_bounds__(512, 8) void conv_fused(
    const unsigned short* __restrict__ h,
    const uint2* __restrict__ gstage, const int* __restrict__ gcnt,
    const unsigned short* __restrict__ WpA,
    const unsigned short* __restrict__ WpB,
    void* __restrict__ outv, int n)
{
    __shared__ unsigned short t1[32 * TS];   // 8.5 KB  z tile
    __shared__ unsigned short t2[32 * TS];   // 8.5 KB  relu(GEMM1) tile
    __shared__ unsigned srt[CAP];            // 3 KB    sorted edge list
    __shared__ int hist[NPB];
    __shared__ int exc[NPB];

    int tid  = threadIdx.x;
    int wave = tid >> 6;
    int lane = tid & 63;
    int qtr  = lane >> 4;       // 0..3 (== MFMA quad)
    int sub  = lane & 15;       // (== MFMA lc)
    int b    = blockIdx.x;
    int nb   = b * 32;

    // ---- mini-sort: bucket entries -> per-node-sorted LDS list ----
    int cnt = min(gcnt[b], CAP);
    if (tid < NPB) hist[tid] = 0;
    __syncthreads();

    uint2 ent[2];
    int   rnk[2];
    int   dl_[2];
#pragma unroll
    for (int it = 0; it < 2; ++it) {
        int i = it * 512 + tid;
        dl_[it] = -1;
        if (i < cnt) {
            ent[it] = gstage[(size_t)b * CAP + i];
            dl_[it] = (ent[it].x >> 16) & 31;
            rnk[it] = atomicAdd(&hist[dl_[it]], 1);
        }
    }
    __syncthreads();

    if (tid < NPB) {
        int v = hist[tid];
#pragma unroll
        for (int dd = 1; dd < NPB; dd <<= 1) {
            int u = __shfl_up(v, dd, 64);
            if (tid >= dd) v += u;
        }
        exc[tid] = v - hist[tid];           // exclusive prefix
    }
    __syncthreads();

#pragma unroll
    for (int it = 0; it < 2; ++it)
        if (dl_[it] >= 0)
            srt[exc[dl_[it]] + rnk[it]] = (ent[it].x & 0xFFFF) | (ent[it].y << 16);
    __syncthreads();

    // ================= gather: one node per quarter, 8-deep =================
    int row  = wave * 4 + qtr;  // 0..31
    int node = nb + row;
    int beg = exc[row];
    int end = beg + hist[row];

    float acc[8];
#pragma unroll
    for (int c = 0; c < 8; ++c) acc[c] = 0.f;

    int i = beg;
    for (; i + 8 <= end; i += 8) {          // 8 rows in flight per quarter
        unsigned p0 = srt[i];
        unsigned p1 = srt[i + 1];
        unsigned p2 = srt[i + 2];
        unsigned p3 = srt[i + 3];
        unsigned p4 = srt[i + 4];
        unsigned p5 = srt[i + 5];
        unsigned p6 = srt[i + 6];
        unsigned p7 = srt[i + 7];
        short8 v0 = ((const short8*)(h + (size_t)(p0 & 0xFFFF) * D))[sub];
        short8 v1 = ((const short8*)(h + (size_t)(p1 & 0xFFFF) * D))[sub];
        short8 v2 = ((const short8*)(h + (size_t)(p2 & 0xFFFF) * D))[sub];
        short8 v3 = ((const short8*)(h + (size_t)(p3 & 0xFFFF) * D))[sub];
        short8 v4 = ((const short8*)(h + (size_t)(p4 & 0xFFFF) * D))[sub];
        short8 v5 = ((const short8*)(h + (size_t)(p5 & 0xFFFF) * D))[sub];
        short8 v6 = ((const short8*)(h + (size_t)(p6 & 0xFFFF) * D))[sub];
        short8 v7 = ((const short8*)(h + (size_t)(p7 & 0xFFFF) * D))[sub];
        float w0 = __half2float(__ushort_as_half((unsigned short)(p0 >> 16)));
        float w1 = __half2float(__ushort_as_half((unsigned short)(p1 >> 16)));
        float w2 = __half2float(__ushort_as_half((unsigned short)(p2 >> 16)));
        float w3 = __half2float(__ushort_as_half((unsigned short)(p3 >> 16)));
        float w4 = __half2float(__ushort_as_half((unsigned short)(p4 >> 16)));
        float w5 = __half2float(__ushort_as_half((unsigned short)(p5 >> 16)));
        float w6 = __half2float(__ushort_as_half((unsigned short)(p6 >> 16)));
        float w7 = __half2float(__ushort_as_half((unsigned short)(p7 >> 16)));
#pragma unroll
        for (int c = 0; c < 8; ++c)
            acc[c] += w0 * bf2f((unsigned short)v0[c]) + w1 * bf2f((unsigned short)v1[c])
                    + w2 * bf2f((unsigned short)v2[c]) + w3 * bf2f((unsigned short)v3[c])
                    + w4 * bf2f((unsigned short)v4[c]) + w5 * bf2f((unsigned short)v5[c])
                    + w6 * bf2f((unsigned short)v6[c]) + w7 * bf2f((unsigned short)v7[c]);
    }
    for (; i + 4 <= end; i += 4) {          // 4 rows in flight
        unsigned p0 = srt[i];
        unsigned p1 = srt[i + 1];
        unsigned p2 = srt[i + 2];
        unsigned p3 = srt[i + 3];
        short8 v0 = ((const short8*)(h + (size_t)(p0 & 0xFFFF) * D))[sub];
        short8 v1 = ((const short8*)(h + (size_t)(p1 & 0xFFFF) * D))[sub];
        short8 v2 = ((const short8*)(h + (size_t)(p2 & 0xFFFF) * D))[sub];
        short8 v3 = ((const short8*)(h + (size_t)(p3 & 0xFFFF) * D))[sub];
        float w0 = __half2float(__ushort_as_half((unsigned short)(p0 >> 16)));
        float w1 = __half2float(__ushort_as_half((unsigned short)(p1 >> 16)));
        float w2 = __half2float(__ushort_as_half((unsigned short)(p2 >> 16)));
        float w3 = __half2float(__ushort_as_half((unsigned short)(p3 >> 16)));
#pragma unroll
        for (int c = 0; c < 8; ++c)
            acc[c] += w0 * bf2f((unsigned short)v0[c]) + w1 * bf2f((unsigned short)v1[c])
                    + w2 * bf2f((unsigned short)v2[c]) + w3 * bf2f((unsigned short)v3[c]);
    }
    for (; i < end; ++i) {                  // <=3 tail edges
        unsigned p0 = srt[i];
        short8 v0 = ((const short8*)(h + (size_t)(p0 & 0xFFFF) * D))[sub];
        float w0 = __half2float(__ushort_as_half((unsigned short)(p0 >> 16)));
#pragma unroll
        for (int c = 0; c < 8; ++c)
            acc[c] += w0 * bf2f((unsigned short)v0[c]);
    }

    // GIN update + store z row (each quarter owns a distinct row)
    {
        const short8 zero8 = {0, 0, 0, 0, 0, 0, 0, 0};
        short8 o;
        if (node < n) {
            short8 xv = ((const short8*)(h + (size_t)node * D))[sub];
#pragma unroll
            for (int c = 0; c < 8; ++c)
                o[c] = (short)f2bf(acc[c] + EPSP1 * bf2f((unsigned short)xv[c]));
        } else {
            o = zero8;
        }
        *(short8*)&t1[row * TS + sub * 8] = o;
    }
    __syncthreads();

    // ================= GEMM1: z @ WpA, relu -> t2 =================
    int cf = wave;              // this wave's column-group
    f32x4 acc2[2];
    acc2[0] = (f32x4){0.f, 0.f, 0.f, 0.f};
    acc2[1] = (f32x4){0.f, 0.f, 0.f, 0.f};

#pragma unroll
    for (int kk = 0; kk < 4; ++kk) {
        short8 a0 = *(const short8*)&t1[(sub)      * TS + kk * 32 + qtr * 8];
        short8 a1 = *(const short8*)&t1[(16 + sub) * TS + kk * 32 + qtr * 8];
        short8 bb = *(const short8*)(WpA + ((size_t)(kk * 4 + qtr) * 128 + cf * 16 + sub) * 8);
        acc2[0] = __builtin_amdgcn_mfma_f32_16x16x32_bf16(a0, bb, acc2[0], 0, 0, 0);
        acc2[1] = __builtin_amdgcn_mfma_f32_16x16x32_bf16(a1, bb, acc2[1], 0, 0, 0);
    }

#pragma unroll
    for (int s = 0; s < 2; ++s)
#pragma unroll
        for (int reg = 0; reg < 4; ++reg) {
            int r = s * 16 + qtr * 4 + reg;
            t2[r * TS + cf * 16 + sub] = f2bf(fmaxf(acc2[s][reg], 0.f));
        }
    __syncthreads();

    // ================= GEMM2: relu(.) @ WpB =================
    acc2[0] = (f32x4){0.f, 0.f, 0.f, 0.f};
    acc2[1] = (f32x4){0.f, 0.f, 0.f, 0.f};

#pragma unroll
    for (int kk = 0; kk < 4; ++kk) {
        short8 a0 = *(const short8*)&t2[(sub)      * TS + kk * 32 + qtr * 8];
        short8 a1 = *(const short8*)&t2[(16 + sub) * TS + kk * 32 + qtr * 8];
        short8 bb = *(const short8*)(WpB + ((size_t)(kk * 4 + qtr) * 128 + cf * 16 + sub) * 8);
        acc2[0] = __builtin_amdgcn_mfma_f32_16x16x32_bf16(a0, bb, acc2[0], 0, 0, 0);
        acc2[1] = __builtin_amdgcn_mfma_f32_16x16x32_bf16(a1, bb, acc2[1], 0, 0, 0);
    }

#pragma unroll
    for (int s = 0; s < 2; ++s)
#pragma unroll
        for (int reg = 0; reg < 4; ++reg) {
            int r = nb + s * 16 + qtr * 4 + reg;
            if (r < n) {
                float v = acc2[s][reg];
                if (RELU2) v = fmaxf(v, 0.f);
                int col = cf * 16 + sub;
                if (OUT_F32)
                    ((float*)outv)[(size_t)r * D + col] = v;
                else
                    ((unsigned short*)outv)[(size_t)r * D + col] = f2bf(v);
            }
        }
}

extern "C" void kernel_launch(void* const* d_in, const int* in_sizes, int n_in,
                              void* d_out, int out_size, void* d_ws, size_t ws_size,
                              hipStream_t stream) {
    const float* x   = (const float*)d_in[0];
    const int*   ei  = (const int*)d_in[1];
    const float* ew  = (const float*)d_in[2];
    const float* W1a = (const float*)d_in[3];
    const float* W1b = (const float*)d_in[4];
    const float* W2a = (const float*)d_in[5];
    const float* W2b = (const float*)d_in[6];
    float* out = (float*)d_out;

    int n_edges = in_sizes[2];                 // 800000
    const int* src = ei;
    const int* dst = ei + n_edges;

    size_t node_elems = (size_t)N_NODES * D;   // 6.4M
    unsigned short* hb = (unsigned short*)d_ws;        // 12.8 MB  bf16 node features
    unsigned short* zb = hb + node_elems;              // 12.8 MB  conv1 output (bf16)
    unsigned short* wp = zb + node_elems;              // 4 x 32 KB packed weights
    uint2*  gstage = (uint2*)(wp + 4 * 16384);         // NBUCK x CAP x 8B staging (9.6 MB)
    int*    gcnt   = (int*)(gstage + (size_t)NBUCK * CAP);  // NBUCK

    int nb1   = (n_edges + P1E - 1) / P1E;              // 196
    int n4    = (int)(node_elems / 4);                  // 1.6M float4
    int ncvt  = (n4 + 4095) / 4096;                     // 391
    int npack = 16;                                     // 8192 short8 / 512
    int cgrid = NBUCK;                                  // 1563 (tile == bucket)

    hipMemsetAsync(gcnt, 0, NBUCK * sizeof(int), stream);

    // ---- pass 1 (merged): per-tile bucket | x->bf16 | weight pack
    pass1_all<<<nb1 + ncvt + npack, 512, 0, stream>>>(
        src, dst, ew, gcnt, gstage, n_edges, nb1,
        x, hb, n4, ncvt, W1a, W1b, W2a, W2b, wp);

    unsigned short* wp0 = wp;
    unsigned short* wp1 = wp + 16384;
    unsigned short* wp2 = wp + 2 * 16384;
    unsigned short* wp3 = wp + 3 * 16384;

    // ---- conv 1 (mini-sort + gather + GIN update + MLP, relu fused)
    conv_fused<1, 0><<<cgrid, 512, 0, stream>>>(hb, gstage, gcnt, wp0, wp1, zb, N_NODES);

    // ---- conv 2 (fp32 out, no final relu)
    conv_fused<0, 1><<<cgrid, 512, 0, stream>>>(zb, gstage, gcnt, wp2, wp3, out, N_NODES);
}